// Round 10
// baseline (457.951 us; speedup 1.0000x reference)
//
#include <hip/hip_runtime.h>
#include <hip/hip_bf16.h>
#include <math.h>

#define B_ 4
#define T_ 4096
#define DM 1024      // d_model
#define DI 2048      // d_inner
#define E2 4096      // 2*d_inner
#define NCHUNK 64
#define CLEN 64

typedef __attribute__((ext_vector_type(8))) short short8;
typedef __attribute__((ext_vector_type(4))) float floatx4;

union bfs { __hip_bfloat16 b; short s; };

__device__ __forceinline__ float bf2f(__hip_bfloat16 x) { return __bfloat162float(x); }
__device__ __forceinline__ short f2s(float x) { bfs u; u.b = __float2bfloat16(x); return u.s; }

__device__ __forceinline__ float ldw(const void* p, int i, int f32m) {
    return f32m ? ((const float*)p)[i] : bf2f(((const __hip_bfloat16*)p)[i]);
}

#define GLDS16(gp, lp) __builtin_amdgcn_global_load_lds( \
    (const __attribute__((address_space(1))) void*)(gp), \
    (__attribute__((address_space(3))) void*)(lp), 16, 0, 0)

#define MEMFENCE asm volatile("" ::: "memory")

// ---------------------------------------------------------------------------
// Input-dtype detector (f32 read as bf16 -> ~44% huge-exponent halves).
// flag = 1 -> inputs are float32, 0 -> bf16.
// ---------------------------------------------------------------------------
__global__ __launch_bounds__(256)
void detect_k(const unsigned short* __restrict__ xu, unsigned* __restrict__ flag)
{
    __shared__ int red[256];
    const int tid = threadIdx.x;
    int cnt = 0;
    for (int i = tid; i < 2048; i += 256) {
        const int e = (xu[i] >> 7) & 0xFF;
        cnt += (e >= 0x90);
    }
    red[tid] = cnt;
    __syncthreads();
    for (int off = 128; off; off >>= 1) {
        if (tid < off) red[tid] += red[tid + off];
        __syncthreads();
    }
    if (tid == 0) *flag = (red[0] >= 8) ? 1u : 0u;
}

// ---------------------------------------------------------------------------
// Dual-mode convert -> contiguous bf16. 8 elems/thread, exact grid.
// ---------------------------------------------------------------------------
__global__ __launch_bounds__(256)
void cvt_k(const void* __restrict__ src, __hip_bfloat16* __restrict__ dst,
           const unsigned* __restrict__ flag)
{
    const int fm = (int)*flag;
    const size_t i0 = ((size_t)blockIdx.x * 256 + threadIdx.x) * 8;
    if (fm) {
        const float* f = (const float*)src + i0;
        floatx4 lo = *(const floatx4*)f;
        floatx4 hi = *(const floatx4*)(f + 4);
        short8 r;
        r[0] = f2s(lo[0]); r[1] = f2s(lo[1]); r[2] = f2s(lo[2]); r[3] = f2s(lo[3]);
        r[4] = f2s(hi[0]); r[5] = f2s(hi[1]); r[6] = f2s(hi[2]); r[7] = f2s(hi[3]);
        *(short8*)(dst + i0) = r;
    } else {
        *(short8*)(dst + i0) = *(const short8*)((const __hip_bfloat16*)src + i0);
    }
}

// ---------------------------------------------------------------------------
// GEMM: C[M,N] = A[M,K] * Bt[N,K]^T — 256x256 tile, BK=32, 8 waves (2Mx4N),
// 4-deep LDS ring pipeline (stage t+3 while computing t), counted vmcnt(8),
// XOR slot-swizzle on LDS (pre-swizzled global source + swizzled ds_read),
// setprio around MFMA clusters. At K=1024/2048 this is at the documented
// achievable range (m248: 8-phase @K=1024 = 848 TF; we measure 892) — parked.
// csel: 1 = C dtype follows flag (f32 when fm), 0 = always bf16.
// ---------------------------------------------------------------------------
__global__ __launch_bounds__(512)
void gemm256(const __hip_bfloat16* __restrict__ A,
             const __hip_bfloat16* __restrict__ Bt,
             void* __restrict__ C, int K, int lda, int ldb, int ldc,
             int csel, const unsigned* __restrict__ flag)
{
    // buffer b: A tile (256x32 bf16 = 16 KB) at b*32768, B tile at +16384
    __shared__ __align__(16) char sL[4 * 32768];   // 128 KB -> 1 block/CU

    const int cf = csel & (int)*flag;

    const int tid  = threadIdx.x;
    const int lane = tid & 63;
    const int wid  = tid >> 6;         // 0..7
    const int wr   = wid >> 2;         // 0..1  (M half)
    const int wc   = wid & 3;          // 0..3  (N quarter)
    const int l15  = lane & 15;
    const int quad = lane >> 4;
    const int swl  = (l15 >> 1) & 3;   // read-side swizzle term

    const int m0 = blockIdx.x * 256;
    const int n0 = blockIdx.y * 256;

    floatx4 acc[8][4];
#pragma unroll
    for (int i = 0; i < 8; i++)
#pragma unroll
        for (int j = 0; j < 4; j++) acc[i][j] = (floatx4){0.f, 0.f, 0.f, 0.f};

    // ---- staging thread mapping (512 thr x 16B = 8 KB = one 128-row half) ----
    const int srow = tid >> 2;                               // 0..127
    const int ksrc = (((tid & 3) ^ ((tid >> 3) & 3))) * 8;   // pre-swizzled col (elems)
    const __hip_bfloat16* gA = A  + (size_t)(m0 + srow) * lda + ksrc;
    const __hip_bfloat16* gB = Bt + (size_t)(n0 + srow) * ldb + ksrc;
    const size_t h1A = (size_t)128 * lda;
    const size_t h1B = (size_t)128 * ldb;

    // wave-uniform LDS staging base (HW adds lane*16): half h at +h*8192
    char* const ldsW = sL + wid * 1024;

    const int NT = K >> 5;

#define STAGE_A(buf, kt) do { \
    const __hip_bfloat16* g_ = gA + (size_t)(kt) * 32; \
    char* l_ = ldsW + (buf) * 32768; \
    GLDS16(g_, l_); \
    GLDS16(g_ + h1A, l_ + 8192); } while (0)
#define STAGE_B(buf, kt) do { \
    const __hip_bfloat16* g_ = gB + (size_t)(kt) * 32; \
    char* l_ = ldsW + (buf) * 32768 + 16384; \
    GLDS16(g_, l_); \
    GLDS16(g_ + h1B, l_ + 8192); } while (0)

    // prologue: tiles 0,1,2 -> bufs 0,1,2 (12 loads); allow 8 newest in flight
    STAGE_A(0, 0); STAGE_B(0, 0);
    STAGE_A(1, 1); STAGE_B(1, 1);
    STAGE_A(2, 2); STAGE_B(2, 2);
    asm volatile("s_waitcnt vmcnt(8)" ::: "memory");   // tile 0 resident
    __builtin_amdgcn_s_barrier();
    MEMFENCE;

    for (int t = 0; t < NT; ++t) {
        const char* Ab = sL + (t & 3) * 32768;
        const char* Bb = Ab + 16384;
        const int nx = (t + 3) & 3;

        // ---------------- phase 0: B-frags + A-frags (m-reps 0-3) ----------
        short8 fb[4], fa[4];
#pragma unroll
        for (int j = 0; j < 4; j++)
            fb[j] = *(const short8*)(Bb + (wc * 64 + j * 16 + l15) * 64 + ((quad ^ swl) * 16));
#pragma unroll
        for (int i = 0; i < 4; i++)
            fa[i] = *(const short8*)(Ab + (wr * 128 + i * 16 + l15) * 64 + ((quad ^ swl) * 16));
        if (t + 3 < NT) STAGE_A(nx, t + 3);
        __builtin_amdgcn_s_barrier();
        MEMFENCE;
        __builtin_amdgcn_s_setprio(1);
#pragma unroll
        for (int i = 0; i < 4; i++)
#pragma unroll
            for (int j = 0; j < 4; j++)
                acc[i][j] = __builtin_amdgcn_mfma_f32_16x16x32_bf16(fa[i], fb[j], acc[i][j], 0, 0, 0);
        __builtin_amdgcn_s_setprio(0);
        __builtin_amdgcn_s_barrier();
        MEMFENCE;

        // ---------------- phase 1: A-frags (m-reps 4-7) --------------------
        short8 fa2[4];
#pragma unroll
        for (int i = 0; i < 4; i++)
            fa2[i] = *(const short8*)(Ab + (wr * 128 + 64 + i * 16 + l15) * 64 + ((quad ^ swl) * 16));
        if (t + 3 < NT) {
            STAGE_B(nx, t + 3);
            asm volatile("s_waitcnt vmcnt(8)" ::: "memory");   // tile t+1 resident
        } else {
            asm volatile("s_waitcnt vmcnt(0)" ::: "memory");   // epilogue drain
        }
        __builtin_amdgcn_s_barrier();
        MEMFENCE;
        __builtin_amdgcn_s_setprio(1);
#pragma unroll
        for (int i = 0; i < 4; i++)
#pragma unroll
            for (int j = 0; j < 4; j++)
                acc[4 + i][j] = __builtin_amdgcn_mfma_f32_16x16x32_bf16(fa2[i], fb[j], acc[4 + i][j], 0, 0, 0);
        __builtin_amdgcn_s_setprio(0);
        __builtin_amdgcn_s_barrier();
        MEMFENCE;
    }
#undef STAGE_A
#undef STAGE_B

    // C/D layout: col = lane&15, row = quad*4 + reg  [m89/m91-verified]
#pragma unroll
    for (int i = 0; i < 8; i++) {
        const int row = m0 + wr * 128 + i * 16 + quad * 4;
#pragma unroll
        for (int j = 0; j < 4; j++) {
            const int col = n0 + wc * 64 + j * 16 + l15;
#pragma unroll
            for (int r = 0; r < 4; r++) {
                const size_t idx = (size_t)(row + r) * ldc + col;
                const float val = acc[i][j][r];
                if (cf) ((float*)C)[idx] = val;
                else    ((__hip_bfloat16*)C)[idx] = __float2bfloat16(val);
            }
        }
    }
}

// ---------------------------------------------------------------------------
// wm[r] = mean_c dtw[c,r]  (r in 0..63, block per r);
// block 64 computes wm[64] = mean(dtb).
// ---------------------------------------------------------------------------
__global__ __launch_bounds__(256)
void precompute_wm_k(const void* __restrict__ dtw, const void* __restrict__ dtb,
                     float* __restrict__ wm, const unsigned* __restrict__ flag)
{
    __shared__ float red[256];
    const int fm = (int)*flag;
    const int tid = threadIdx.x;
    const int r = blockIdx.x;              // 0..64
    float s = 0.f;
    if (r < 64) {
        for (int c = tid; c < DI; c += 256) s += ldw(dtw, c * 64 + r, fm);
    } else {
        for (int c = tid; c < DI; c += 256) s += ldw(dtb, c, fm);
    }
    red[tid] = s;
    __syncthreads();
    for (int off = 128; off; off >>= 1) {
        if (tid < off) red[tid] += red[tid + off];
        __syncthreads();
    }
    if (tid == 0) wm[r] = red[0] / (float)DI;
}

// ---------------------------------------------------------------------------
// v[c] = sum_r wm[r] * xpw[r*DI + c];  v[DI] = wm[64] (dtb mean).
// Also emits u_k[c] = v[c]*cw[c,k] (k=0..2) and per-block partials of
// sum_c v[c]*cb[c] into gcpart[8] (deterministic, no atomics).
// ---------------------------------------------------------------------------
__global__ __launch_bounds__(256)
void precompute_v2_k(const void* __restrict__ xpw, const float* __restrict__ wm,
                     const void* __restrict__ cw, const void* __restrict__ cb,
                     float* __restrict__ v,
                     float* __restrict__ u0, float* __restrict__ u1,
                     float* __restrict__ u2, float* __restrict__ gcpart,
                     const unsigned* __restrict__ flag)
{
    __shared__ float red[256];
    const int fm = (int)*flag;
    const int tid = threadIdx.x;
    const int c = blockIdx.x * 256 + tid;           // 0..2047
    float s = 0.f;
#pragma unroll
    for (int r = 0; r < 64; r++) s += wm[r] * ldw(xpw, r * DI + c, fm);
    v[c] = s;
    u0[c] = s * ldw(cw, c * 3 + 0, fm);
    u1[c] = s * ldw(cw, c * 3 + 1, fm);
    u2[c] = s * ldw(cw, c * 3 + 2, fm);
    if (c == 0) v[DI] = wm[64];

    red[tid] = s * ldw(cb, c, fm);
    __syncthreads();
    for (int off = 128; off; off >>= 1) {
        if (tid < off) red[tid] += red[tid + off];
        __syncthreads();
    }
    if (tid == 0) gcpart[blockIdx.x] = red[0];
}

// ---------------------------------------------------------------------------
// S_k[b,t] = dot(u_k, xrow[b,t]) for k=0..2.  8 t-rows per block: u loaded
// ONCE into 24 regs and reused 8x (u L2 traffic /8, dispatch rounds /8).
// One __syncthreads per block (wave partials parked in red[96]).
// ---------------------------------------------------------------------------
__global__ __launch_bounds__(256)
void gate_dots_k(const __hip_bfloat16* __restrict__ xz,
                 const float* __restrict__ u0, const float* __restrict__ u1,
                 const float* __restrict__ u2,
                 float* __restrict__ S0, float* __restrict__ S1,
                 float* __restrict__ S2)
{
    __shared__ float red[96];                 // 4 waves x 8 rows x 3 sums
    const int t0 = blockIdx.x * 8;            // grid.x = 512
    const int b = blockIdx.y, tid = threadIdx.x;
    const size_t bt0 = (size_t)b * T_ + t0;
    const int c0 = tid * 8;
    const floatx4 a0 = *(const floatx4*)(u0 + c0);
    const floatx4 b0 = *(const floatx4*)(u0 + c0 + 4);
    const floatx4 a1 = *(const floatx4*)(u1 + c0);
    const floatx4 b1 = *(const floatx4*)(u1 + c0 + 4);
    const floatx4 a2 = *(const floatx4*)(u2 + c0);
    const floatx4 b2 = *(const floatx4*)(u2 + c0 + 4);
    const __hip_bfloat16* xrow = xz + bt0 * E2 + c0;
    const int wv = tid >> 6;

#pragma unroll
    for (int rr = 0; rr < 8; rr++) {
        const short8 xv = *(const short8*)(xrow + (size_t)rr * E2);
        float s0 = 0.f, s1 = 0.f, s2 = 0.f;
#pragma unroll
        for (int j = 0; j < 4; j++) {
            bfs w; w.s = xv[j];
            const float xf = bf2f(w.b);
            s0 += a0[j] * xf; s1 += a1[j] * xf; s2 += a2[j] * xf;
        }
#pragma unroll
        for (int j = 0; j < 4; j++) {
            bfs w; w.s = xv[4 + j];
            const float xf = bf2f(w.b);
            s0 += b0[j] * xf; s1 += b1[j] * xf; s2 += b2[j] * xf;
        }
#pragma unroll
        for (int off = 32; off; off >>= 1) {
            s0 += __shfl_xor(s0, off);
            s1 += __shfl_xor(s1, off);
            s2 += __shfl_xor(s2, off);
        }
        if ((tid & 63) == 0) {
            red[wv * 24 + rr * 3 + 0] = s0;
            red[wv * 24 + rr * 3 + 1] = s1;
            red[wv * 24 + rr * 3 + 2] = s2;
        }
    }
    __syncthreads();
    if (tid < 24) {
        const int rr = tid / 3, k = tid - rr * 3;
        const float r = red[tid] + red[24 + tid] + red[48 + tid] + red[72 + tid];
        float* Sk = (k == 0) ? S0 : (k == 1) ? S1 : S2;
        Sk[bt0 + rr] = r;
    }
}

// ---------------------------------------------------------------------------
// gate[b,t] = sigmoid(S0[b,t-1] + S1[b,t] + S2[b,t+1] + sum(gcpart) + v[DI]);
// each 64-lane wave covers exactly one chunk -> P computed via shfl product.
// ---------------------------------------------------------------------------
__global__ __launch_bounds__(256)
void gate_fin_k(const float* __restrict__ S0, const float* __restrict__ S1,
                const float* __restrict__ S2, const float* __restrict__ gcpart,
                const float* __restrict__ v, float* __restrict__ gate,
                float* __restrict__ P)
{
    const int gid = blockIdx.x * 256 + threadIdx.x;   // 16384 = B_*T_
    const int t = gid & (T_ - 1);
    float k = v[DI];
#pragma unroll
    for (int i = 0; i < 8; i++) k += gcpart[i];
    float lg = S1[gid] + k;
    if (t > 0)      lg += S0[gid - 1];
    if (t < T_ - 1) lg += S2[gid + 1];
    const float g = 1.f / (1.f + __expf(-lg));
    gate[gid] = g;

    float p = g;
#pragma unroll
    for (int off = 32; off; off >>= 1) p *= __shfl_xor(p, off);
    if ((threadIdx.x & 63) == 0) {
        const int b = gid >> 12;              // / T_
        const int ch = t >> 6;                // / CLEN
        P[b * NCHUNK + ch] = p;
    }
}

// ---------------------------------------------------------------------------
// Pass A: per-chunk local scan from h=0 (conv recomputed on the fly);
// store chunk-end value r[b,chunk,c]. Reads x-half of xz only.
// (R6 scalar config: 2048 blocks = full 32-wave/CU occupancy — proven best.)
// ---------------------------------------------------------------------------
__global__ __launch_bounds__(256)
void scan_chunks(const __hip_bfloat16* __restrict__ xz,
                 const float* __restrict__ gate,
                 const void* __restrict__ cw, const void* __restrict__ cb,
                 float* __restrict__ r, const unsigned* __restrict__ flag)
{
    const int fm = (int)*flag;
    const int blk = blockIdx.x;               // 2048 = B_*NCHUNK*8
    const int cg = blk & 7, chunk = (blk >> 3) & 63, b = blk >> 9;
    const int c = cg * 256 + threadIdx.x;
    const float w0 = ldw(cw, c * 3 + 0, fm);
    const float w1 = ldw(cw, c * 3 + 1, fm);
    const float w2 = ldw(cw, c * 3 + 2, fm);
    const float bc = ldw(cb, c, fm);
    const int t0 = chunk * CLEN;
    const float* g = gate + (size_t)b * T_ + t0;
    const __hip_bfloat16* px = xz + (size_t)b * T_ * E2 + c;

    float xm = (t0 > 0) ? bf2f(px[(size_t)(t0 - 1) * E2]) : 0.f;
    float xc = bf2f(px[(size_t)t0 * E2]);
    float h = 0.f;
#pragma unroll 4
    for (int i = 0; i < CLEN; i++) {
        const int t = t0 + i;
        const float xn = (t + 1 < T_) ? bf2f(px[(size_t)(t + 1) * E2]) : 0.f;
        const float val = w0 * xm + w1 * xc + w2 * xn + bc;
        const float gi = g[i];
        h = gi * h + (1.f - gi) * val;
        xm = xc; xc = xn;
    }
    r[((size_t)b * NCHUNK + chunk) * DI + c] = h;
}

// ---------------------------------------------------------------------------
// Pass B: preload all 64 rk into registers (pipelined, ~2 latency round
// trips instead of 64 serial ones) + P row in LDS, then run the h-chain.
// In-place r[b,k,c] := h_in of chunk k. Same arithmetic order as before.
// ---------------------------------------------------------------------------
__global__ __launch_bounds__(256)
void carry_fix(float* __restrict__ r, const float* __restrict__ P)
{
    __shared__ float Ps[NCHUNK];
    const int gid = blockIdx.x * 256 + threadIdx.x;   // 8192 = B_*DI
    const int b = gid >> 11, c = gid & 2047;
    if (threadIdx.x < NCHUNK) Ps[threadIdx.x] = P[b * NCHUNK + threadIdx.x];
    __syncthreads();

    float* base = r + (size_t)b * NCHUNK * DI + c;
    float rk[NCHUNK];
#pragma unroll
    for (int k = 0; k < NCHUNK; k++) rk[k] = base[(size_t)k * DI];
    float h = 0.f;
#pragma unroll
    for (int k = 0; k < NCHUNK; k++) {
        base[(size_t)k * DI] = h;
        h = Ps[k] * h + rk[k];
    }
}

// ---------------------------------------------------------------------------
// Pass C: re-scan with carry-in; y = h*silu(z) + D*val written over the
// Z-HALF slot it just read (x-half stays intact -> conv reads race-free).
// (R6 scalar config — proven best.)
// ---------------------------------------------------------------------------
__global__ __launch_bounds__(256)
void scan_apply(__hip_bfloat16* __restrict__ xz,
                const float* __restrict__ gate,
                const float* __restrict__ r,
                const void* __restrict__ cw, const void* __restrict__ cb,
                const void* __restrict__ Dp, const unsigned* __restrict__ flag)
{
    const int fm = (int)*flag;
    const int blk = blockIdx.x;               // 2048
    const int cg = blk & 7, chunk = (blk >> 3) & 63, b = blk >> 9;
    const int c = cg * 256 + threadIdx.x;
    const float w0 = ldw(cw, c * 3 + 0, fm);
    const float w1 = ldw(cw, c * 3 + 1, fm);
    const float w2 = ldw(cw, c * 3 + 2, fm);
    const float bc = ldw(cb, c, fm);
    const float Dc = ldw(Dp, c, fm);
    const int t0 = chunk * CLEN;
    const float* g = gate + (size_t)b * T_ + t0;
    const __hip_bfloat16* px = xz + (size_t)b * T_ * E2 + c;            // x-half
    __hip_bfloat16* pz = xz + (size_t)b * T_ * E2 + DI + c;             // z-half

    float h = r[((size_t)b * NCHUNK + chunk) * DI + c];
    float xm = (t0 > 0) ? bf2f(px[(size_t)(t0 - 1) * E2]) : 0.f;
    float xc = bf2f(px[(size_t)t0 * E2]);
#pragma unroll 4
    for (int i = 0; i < CLEN; i++) {
        const int t = t0 + i;
        const float xn = (t + 1 < T_) ? bf2f(px[(size_t)(t + 1) * E2]) : 0.f;
        const float val = w0 * xm + w1 * xc + w2 * xn + bc;
        const float gi = g[i];
        h = gi * h + (1.f - gi) * val;
        const float zv = bf2f(pz[(size_t)t * E2]);
        const float sil = zv / (1.f + __expf(-zv));
        pz[(size_t)t * E2] = __float2bfloat16(h * sil + Dc * val);
        xm = xc; xc = xn;
    }
}

// ---------------------------------------------------------------------------
extern "C" void kernel_launch(void* const* d_in, const int* in_sizes, int n_in,
                              void* d_out, int out_size, void* d_ws, size_t ws_size,
                              hipStream_t stream)
{
    // ws layout (proven size): xz[0,134217728) gate[..+65536) v[..+8704) flag
    const size_t REQUIRED = 134292480;
    if (ws_size < REQUIRED) return;   // finite-absmax diagnostic signature

    const void* x    = d_in[0];
    const void* wip  = d_in[1];  // [4096,1024]
    const void* cw   = d_in[2];  // [2048,1,3]
    const void* cb   = d_in[3];
    const void* xpw  = d_in[4];  // [96,2048]
    const void* dtw  = d_in[5];  // [2048,64]
    const void* dtb  = d_in[6];
    const void* Dp   = d_in[7];
    const void* wop  = d_in[8];  // [1024,2048]

    char* ws = (char*)d_ws;
    __hip_bfloat16* xz = (__hip_bfloat16*)ws;
    float* gate    = (float*)(ws + 134217728);
    float* v       = (float*)(ws + 134283264);
    float* wm      = v + 2052;                 // 65 floats, fits in v's 8704 B region
    unsigned* flag = (unsigned*)(ws + 134291968);

    // d_out scratch (67.1 MB, all dead before gemm2 writes final out):
    //   x_bf16   [0, 33554432)          16.8M elems
    //   wip_bf16 [33554432, 41943040)    4.2M elems
    //   r        [41943040, 44040192)    2 MB
    //   P        [44040192, 44041216)    1 KB
    //   u0/u1/u2 [44041216, 44065792)    3 x 8 KB
    //   gcpart   [44065792, 44065824)    32 B
    //   S0/S1/S2 [44065824, 44262432)    3 x 64 KB
    //   wop_bf16 [44262432, 48456736)    2.1M elems (contiguous, ldb=2048)
    __hip_bfloat16* x_bf   = (__hip_bfloat16*)d_out;
    __hip_bfloat16* wip_bf = (__hip_bfloat16*)((char*)d_out + 33554432);
    float* r      = (float*)((char*)d_out + 41943040);
    float* P      = (float*)((char*)d_out + 44040192);
    float* u0     = (float*)((char*)d_out + 44041216);
    float* u1     = (float*)((char*)d_out + 44049408);
    float* u2     = (float*)((char*)d_out + 44057600);
    float* gcpart = (float*)((char*)d_out + 44065792);
    float* S0     = (float*)((char*)d_out + 44065824);
    float* S1     = (float*)((char*)d_out + 44131360);
    float* S2     = (float*)((char*)d_out + 44196896);
    __hip_bfloat16* wop_bf = (__hip_bfloat16*)((char*)d_out + 44262432);

    detect_k<<<1, 256, 0, stream>>>((const unsigned short*)x, flag);

    // all conversions up front (wop off the critical path, contiguous rows)
    cvt_k<<<8192, 256, 0, stream>>>(x, x_bf, flag);       // 16777216 elems
    cvt_k<<<2048, 256, 0, stream>>>(wip, wip_bf, flag);   //  4194304 elems
    cvt_k<<<1024, 256, 0, stream>>>(wop, wop_bf, flag);   //  2097152 elems

    // precompute v: 65-block column-mean reduce, then 8-block mat-vec (+ u, cb-sum)
    precompute_wm_k<<<65, 256, 0, stream>>>(dtw, dtb, wm, flag);
    precompute_v2_k<<<8, 256, 0, stream>>>(xpw, wm, cw, cb, v, u0, u1, u2,
                                           gcpart, flag);

    // xz[16384,4096] = x_bf[16384,1024] * wip_bf^T   (C bf16)
    gemm256<<<dim3(64, 16), 512, 0, stream>>>(x_bf, wip_bf, xz,
                                              1024, 1024, 1024, E2, 0, flag);

    // gate: 8-row blocks with u-reuse -> boundary combine (+ fused P product)
    gate_dots_k<<<dim3(512, B_), 256, 0, stream>>>(xz, u0, u1, u2, S0, S1, S2);
    gate_fin_k<<<64, 256, 0, stream>>>(S0, S1, S2, gcpart, v, gate, P);

    scan_chunks<<<2048, 256, 0, stream>>>(xz, gate, cw, cb, r, flag);
    carry_fix<<<32, 256, 0, stream>>>(r, P);
    scan_apply<<<2048, 256, 0, stream>>>(xz, gate, r, cw, cb, Dp, flag);

    // out[16384,1024] = y[16384,2048](z-half, stride E2) * wop_bf^T (ldb=2048)
    gemm256<<<dim3(64, 4), 512, 0, stream>>>(xz + DI, wop_bf, d_out,
                                             2048, E2, 2048, DM, 1, flag);
}

// Round 11
// 440.400 us; speedup vs baseline: 1.0399x; 1.0399x over previous
//
#include <hip/hip_runtime.h>
#include <hip/hip_bf16.h>
#include <math.h>

#define B_ 4
#define T_ 4096
#define DM 1024      // d_model
#define DI 2048      // d_inner
#define E2 4096      // 2*d_inner
#define NCHUNK 64
#define CLEN 64

typedef __attribute__((ext_vector_type(8))) short short8;
typedef __attribute__((ext_vector_type(4))) float floatx4;

union bfs { __hip_bfloat16 b; short s; };

__device__ __forceinline__ float bf2f(__hip_bfloat16 x) { return __bfloat162float(x); }
__device__ __forceinline__ short f2s(float x) { bfs u; u.b = __float2bfloat16(x); return u.s; }

__device__ __forceinline__ float ldw(const void* p, int i, int f32m) {
    return f32m ? ((const float*)p)[i] : bf2f(((const __hip_bfloat16*)p)[i]);
}

#define GLDS16(gp, lp) __builtin_amdgcn_global_load_lds( \
    (const __attribute__((address_space(1))) void*)(gp), \
    (__attribute__((address_space(3))) void*)(lp), 16, 0, 0)

#define MEMFENCE asm volatile("" ::: "memory")

// ---------------------------------------------------------------------------
// Input-dtype detector (f32 read as bf16 -> ~44% huge-exponent halves).
// flag = 1 -> inputs are float32, 0 -> bf16.
// ---------------------------------------------------------------------------
__global__ __launch_bounds__(256)
void detect_k(const unsigned short* __restrict__ xu, unsigned* __restrict__ flag)
{
    __shared__ int red[256];
    const int tid = threadIdx.x;
    int cnt = 0;
    for (int i = tid; i < 2048; i += 256) {
        const int e = (xu[i] >> 7) & 0xFF;
        cnt += (e >= 0x90);
    }
    red[tid] = cnt;
    __syncthreads();
    for (int off = 128; off; off >>= 1) {
        if (tid < off) red[tid] += red[tid + off];
        __syncthreads();
    }
    if (tid == 0) *flag = (red[0] >= 8) ? 1u : 0u;
}

// ---------------------------------------------------------------------------
// Dual-mode convert -> contiguous bf16. 8 elems/thread, exact grid.
// ---------------------------------------------------------------------------
__global__ __launch_bounds__(256)
void cvt_k(const void* __restrict__ src, __hip_bfloat16* __restrict__ dst,
           const unsigned* __restrict__ flag)
{
    const int fm = (int)*flag;
    const size_t i0 = ((size_t)blockIdx.x * 256 + threadIdx.x) * 8;
    if (fm) {
        const float* f = (const float*)src + i0;
        floatx4 lo = *(const floatx4*)f;
        floatx4 hi = *(const floatx4*)(f + 4);
        short8 r;
        r[0] = f2s(lo[0]); r[1] = f2s(lo[1]); r[2] = f2s(lo[2]); r[3] = f2s(lo[3]);
        r[4] = f2s(hi[0]); r[5] = f2s(hi[1]); r[6] = f2s(hi[2]); r[7] = f2s(hi[3]);
        *(short8*)(dst + i0) = r;
    } else {
        *(short8*)(dst + i0) = *(const short8*)((const __hip_bfloat16*)src + i0);
    }
}

// Dual-mode convert wop[1024,2048] -> bf16 rows at dst row-pitch E2.
__global__ __launch_bounds__(256)
void cvt_strided_k(const void* __restrict__ src, __hip_bfloat16* __restrict__ dst,
                   const unsigned* __restrict__ flag)
{
    const int fm = (int)*flag;
    const size_t i0 = ((size_t)blockIdx.x * 256 + threadIdx.x) * 8;  // < 2097152
    const size_t row = i0 >> 11, col = i0 & 2047;
    __hip_bfloat16* d = dst + row * E2 + col;
    if (fm) {
        const float* f = (const float*)src + i0;
        floatx4 lo = *(const floatx4*)f;
        floatx4 hi = *(const floatx4*)(f + 4);
        short8 r;
        r[0] = f2s(lo[0]); r[1] = f2s(lo[1]); r[2] = f2s(lo[2]); r[3] = f2s(lo[3]);
        r[4] = f2s(hi[0]); r[5] = f2s(hi[1]); r[6] = f2s(hi[2]); r[7] = f2s(hi[3]);
        *(short8*)d = r;
    } else {
        *(short8*)d = *(const short8*)((const __hip_bfloat16*)src + i0);
    }
}

// ---------------------------------------------------------------------------
// GEMM: C[M,N] = A[M,K] * Bt[N,K]^T — 256x256 tile, BK=32, 8 waves (2Mx4N),
// 4-deep LDS ring pipeline (stage t+3 while computing t), counted vmcnt(8),
// XOR slot-swizzle on LDS (pre-swizzled global source + swizzled ds_read),
// setprio around MFMA clusters. At K=1024/2048 this is at the documented
// achievable range (m248: 8-phase @K=1024 = 848 TF; we measure 892) — parked.
// csel: 1 = C dtype follows flag (f32 when fm), 0 = always bf16.
// ---------------------------------------------------------------------------
__global__ __launch_bounds__(512)
void gemm256(const __hip_bfloat16* __restrict__ A,
             const __hip_bfloat16* __restrict__ Bt,
             void* __restrict__ C, int K, int lda, int ldb, int ldc,
             int csel, const unsigned* __restrict__ flag)
{
    // buffer b: A tile (256x32 bf16 = 16 KB) at b*32768, B tile at +16384
    __shared__ __align__(16) char sL[4 * 32768];   // 128 KB -> 1 block/CU

    const int cf = csel & (int)*flag;

    const int tid  = threadIdx.x;
    const int lane = tid & 63;
    const int wid  = tid >> 6;         // 0..7
    const int wr   = wid >> 2;         // 0..1  (M half)
    const int wc   = wid & 3;          // 0..3  (N quarter)
    const int l15  = lane & 15;
    const int quad = lane >> 4;
    const int swl  = (l15 >> 1) & 3;   // read-side swizzle term

    const int m0 = blockIdx.x * 256;
    const int n0 = blockIdx.y * 256;

    floatx4 acc[8][4];
#pragma unroll
    for (int i = 0; i < 8; i++)
#pragma unroll
        for (int j = 0; j < 4; j++) acc[i][j] = (floatx4){0.f, 0.f, 0.f, 0.f};

    // ---- staging thread mapping (512 thr x 16B = 8 KB = one 128-row half) ----
    const int srow = tid >> 2;                               // 0..127
    const int ksrc = (((tid & 3) ^ ((tid >> 3) & 3))) * 8;   // pre-swizzled col (elems)
    const __hip_bfloat16* gA = A  + (size_t)(m0 + srow) * lda + ksrc;
    const __hip_bfloat16* gB = Bt + (size_t)(n0 + srow) * ldb + ksrc;
    const size_t h1A = (size_t)128 * lda;
    const size_t h1B = (size_t)128 * ldb;

    // wave-uniform LDS staging base (HW adds lane*16): half h at +h*8192
    char* const ldsW = sL + wid * 1024;

    const int NT = K >> 5;

#define STAGE_A(buf, kt) do { \
    const __hip_bfloat16* g_ = gA + (size_t)(kt) * 32; \
    char* l_ = ldsW + (buf) * 32768; \
    GLDS16(g_, l_); \
    GLDS16(g_ + h1A, l_ + 8192); } while (0)
#define STAGE_B(buf, kt) do { \
    const __hip_bfloat16* g_ = gB + (size_t)(kt) * 32; \
    char* l_ = ldsW + (buf) * 32768 + 16384; \
    GLDS16(g_, l_); \
    GLDS16(g_ + h1B, l_ + 8192); } while (0)

    // prologue: tiles 0,1,2 -> bufs 0,1,2 (12 loads); allow 8 newest in flight
    STAGE_A(0, 0); STAGE_B(0, 0);
    STAGE_A(1, 1); STAGE_B(1, 1);
    STAGE_A(2, 2); STAGE_B(2, 2);
    asm volatile("s_waitcnt vmcnt(8)" ::: "memory");   // tile 0 resident
    __builtin_amdgcn_s_barrier();
    MEMFENCE;

    for (int t = 0; t < NT; ++t) {
        const char* Ab = sL + (t & 3) * 32768;
        const char* Bb = Ab + 16384;
        const int nx = (t + 3) & 3;

        // ---------------- phase 0: B-frags + A-frags (m-reps 0-3) ----------
        short8 fb[4], fa[4];
#pragma unroll
        for (int j = 0; j < 4; j++)
            fb[j] = *(const short8*)(Bb + (wc * 64 + j * 16 + l15) * 64 + ((quad ^ swl) * 16));
#pragma unroll
        for (int i = 0; i < 4; i++)
            fa[i] = *(const short8*)(Ab + (wr * 128 + i * 16 + l15) * 64 + ((quad ^ swl) * 16));
        if (t + 3 < NT) STAGE_A(nx, t + 3);
        __builtin_amdgcn_s_barrier();
        MEMFENCE;
        __builtin_amdgcn_s_setprio(1);
#pragma unroll
        for (int i = 0; i < 4; i++)
#pragma unroll
            for (int j = 0; j < 4; j++)
                acc[i][j] = __builtin_amdgcn_mfma_f32_16x16x32_bf16(fa[i], fb[j], acc[i][j], 0, 0, 0);
        __builtin_amdgcn_s_setprio(0);
        __builtin_amdgcn_s_barrier();
        MEMFENCE;

        // ---------------- phase 1: A-frags (m-reps 4-7) --------------------
        short8 fa2[4];
#pragma unroll
        for (int i = 0; i < 4; i++)
            fa2[i] = *(const short8*)(Ab + (wr * 128 + 64 + i * 16 + l15) * 64 + ((quad ^ swl) * 16));
        if (t + 3 < NT) {
            STAGE_B(nx, t + 3);
            asm volatile("s_waitcnt vmcnt(8)" ::: "memory");   // tile t+1 resident
        } else {
            asm volatile("s_waitcnt vmcnt(0)" ::: "memory");   // epilogue drain
        }
        __builtin_amdgcn_s_barrier();
        MEMFENCE;
        __builtin_amdgcn_s_setprio(1);
#pragma unroll
        for (int i = 0; i < 4; i++)
#pragma unroll
            for (int j = 0; j < 4; j++)
                acc[4 + i][j] = __builtin_amdgcn_mfma_f32_16x16x32_bf16(fa2[i], fb[j], acc[4 + i][j], 0, 0, 0);
        __builtin_amdgcn_s_setprio(0);
        __builtin_amdgcn_s_barrier();
        MEMFENCE;
    }
#undef STAGE_A
#undef STAGE_B

    // C/D layout: col = lane&15, row = quad*4 + reg  [m89/m91-verified]
#pragma unroll
    for (int i = 0; i < 8; i++) {
        const int row = m0 + wr * 128 + i * 16 + quad * 4;
#pragma unroll
        for (int j = 0; j < 4; j++) {
            const int col = n0 + wc * 64 + j * 16 + l15;
#pragma unroll
            for (int r = 0; r < 4; r++) {
                const size_t idx = (size_t)(row + r) * ldc + col;
                const float val = acc[i][j][r];
                if (cf) ((float*)C)[idx] = val;
                else    ((__hip_bfloat16*)C)[idx] = __float2bfloat16(val);
            }
        }
    }
}

// ---------------------------------------------------------------------------
// wm[r] = mean_c dtw[c,r]  (r in 0..63, block per r);
// block 64 computes wm[64] = mean(dtb).
// ---------------------------------------------------------------------------
__global__ __launch_bounds__(256)
void precompute_wm_k(const void* __restrict__ dtw, const void* __restrict__ dtb,
                     float* __restrict__ wm, const unsigned* __restrict__ flag)
{
    __shared__ float red[256];
    const int fm = (int)*flag;
    const int tid = threadIdx.x;
    const int r = blockIdx.x;              // 0..64
    float s = 0.f;
    if (r < 64) {
        for (int c = tid; c < DI; c += 256) s += ldw(dtw, c * 64 + r, fm);
    } else {
        for (int c = tid; c < DI; c += 256) s += ldw(dtb, c, fm);
    }
    red[tid] = s;
    __syncthreads();
    for (int off = 128; off; off >>= 1) {
        if (tid < off) red[tid] += red[tid + off];
        __syncthreads();
    }
    if (tid == 0) wm[r] = red[0] / (float)DI;
}

// ---------------------------------------------------------------------------
// v[c] = sum_r wm[r] * xpw[r*DI + c];  v[DI] = wm[64] (dtb mean).
// Also emits u_k[c] = v[c]*cw[c,k] (k=0..2) and per-block partials of
// sum_c v[c]*cb[c] into gcpart[8] (deterministic, no atomics).
// ---------------------------------------------------------------------------
__global__ __launch_bounds__(256)
void precompute_v2_k(const void* __restrict__ xpw, const float* __restrict__ wm,
                     const void* __restrict__ cw, const void* __restrict__ cb,
                     float* __restrict__ v,
                     float* __restrict__ u0, float* __restrict__ u1,
                     float* __restrict__ u2, float* __restrict__ gcpart,
                     const unsigned* __restrict__ flag)
{
    __shared__ float red[256];
    const int fm = (int)*flag;
    const int tid = threadIdx.x;
    const int c = blockIdx.x * 256 + tid;           // 0..2047
    float s = 0.f;
#pragma unroll
    for (int r = 0; r < 64; r++) s += wm[r] * ldw(xpw, r * DI + c, fm);
    v[c] = s;
    u0[c] = s * ldw(cw, c * 3 + 0, fm);
    u1[c] = s * ldw(cw, c * 3 + 1, fm);
    u2[c] = s * ldw(cw, c * 3 + 2, fm);
    if (c == 0) v[DI] = wm[64];

    red[tid] = s * ldw(cb, c, fm);
    __syncthreads();
    for (int off = 128; off; off >>= 1) {
        if (tid < off) red[tid] += red[tid + off];
        __syncthreads();
    }
    if (tid == 0) gcpart[blockIdx.x] = red[0];
}

// ---------------------------------------------------------------------------
// S_k[b,t] = dot(u_k, xrow[b,t]) for k=0..2.  4 t-rows per block: u loaded
// ONCE into 24 regs and reused 4x (u L2 traffic /4, dispatch rounds /4).
// One __syncthreads per block (wave partials parked in red[48]).  [R9-proven]
// ---------------------------------------------------------------------------
__global__ __launch_bounds__(256)
void gate_dots_k(const __hip_bfloat16* __restrict__ xz,
                 const float* __restrict__ u0, const float* __restrict__ u1,
                 const float* __restrict__ u2,
                 float* __restrict__ S0, float* __restrict__ S1,
                 float* __restrict__ S2)
{
    __shared__ float red[48];                 // 4 waves x 4 rows x 3 sums
    const int t0 = blockIdx.x * 4;            // grid.x = 1024
    const int b = blockIdx.y, tid = threadIdx.x;
    const size_t bt0 = (size_t)b * T_ + t0;
    const int c0 = tid * 8;
    const floatx4 a0 = *(const floatx4*)(u0 + c0);
    const floatx4 b0 = *(const floatx4*)(u0 + c0 + 4);
    const floatx4 a1 = *(const floatx4*)(u1 + c0);
    const floatx4 b1 = *(const floatx4*)(u1 + c0 + 4);
    const floatx4 a2 = *(const floatx4*)(u2 + c0);
    const floatx4 b2 = *(const floatx4*)(u2 + c0 + 4);
    const __hip_bfloat16* xrow = xz + bt0 * E2 + c0;
    const int wv = tid >> 6;

#pragma unroll
    for (int rr = 0; rr < 4; rr++) {
        const short8 xv = *(const short8*)(xrow + (size_t)rr * E2);
        float s0 = 0.f, s1 = 0.f, s2 = 0.f;
#pragma unroll
        for (int j = 0; j < 4; j++) {
            bfs w; w.s = xv[j];
            const float xf = bf2f(w.b);
            s0 += a0[j] * xf; s1 += a1[j] * xf; s2 += a2[j] * xf;
        }
#pragma unroll
        for (int j = 0; j < 4; j++) {
            bfs w; w.s = xv[4 + j];
            const float xf = bf2f(w.b);
            s0 += b0[j] * xf; s1 += b1[j] * xf; s2 += b2[j] * xf;
        }
#pragma unroll
        for (int off = 32; off; off >>= 1) {
            s0 += __shfl_xor(s0, off);
            s1 += __shfl_xor(s1, off);
            s2 += __shfl_xor(s2, off);
        }
        if ((tid & 63) == 0) {
            red[wv * 12 + rr * 3 + 0] = s0;
            red[wv * 12 + rr * 3 + 1] = s1;
            red[wv * 12 + rr * 3 + 2] = s2;
        }
    }
    __syncthreads();
    if (tid < 12) {
        const int rr = tid / 3, k = tid - rr * 3;
        const float r = red[tid] + red[12 + tid] + red[24 + tid] + red[36 + tid];
        float* Sk = (k == 0) ? S0 : (k == 1) ? S1 : S2;
        Sk[bt0 + rr] = r;
    }
}

// ---------------------------------------------------------------------------
// gate[b,t] = sigmoid(S0[b,t-1] + S1[b,t] + S2[b,t+1] + sum(gcpart) + v[DI]);
// each 64-lane wave covers exactly one chunk -> P computed via shfl product.
// ---------------------------------------------------------------------------
__global__ __launch_bounds__(256)
void gate_fin_k(const float* __restrict__ S0, const float* __restrict__ S1,
                const float* __restrict__ S2, const float* __restrict__ gcpart,
                const float* __restrict__ v, float* __restrict__ gate,
                float* __restrict__ P)
{
    const int gid = blockIdx.x * 256 + threadIdx.x;   // 16384 = B_*T_
    const int t = gid & (T_ - 1);
    float k = v[DI];
#pragma unroll
    for (int i = 0; i < 8; i++) k += gcpart[i];
    float lg = S1[gid] + k;
    if (t > 0)      lg += S0[gid - 1];
    if (t < T_ - 1) lg += S2[gid + 1];
    const float g = 1.f / (1.f + __expf(-lg));
    gate[gid] = g;

    float p = g;
#pragma unroll
    for (int off = 32; off; off >>= 1) p *= __shfl_xor(p, off);
    if ((threadIdx.x & 63) == 0) {
        const int b = gid >> 12;              // / T_
        const int ch = t >> 6;                // / CLEN
        P[b * NCHUNK + ch] = p;
    }
}

// ---------------------------------------------------------------------------
// Pass A: per-chunk local scan from h=0 (conv recomputed on the fly);
// store chunk-end value r[b,chunk,c]. Reads x-half of xz only.
// (R6 scalar config: 2048 blocks = full 32-wave/CU occupancy — proven best.)
// ---------------------------------------------------------------------------
__global__ __launch_bounds__(256)
void scan_chunks(const __hip_bfloat16* __restrict__ xz,
                 const float* __restrict__ gate,
                 const void* __restrict__ cw, const void* __restrict__ cb,
                 float* __restrict__ r, const unsigned* __restrict__ flag)
{
    const int fm = (int)*flag;
    const int blk = blockIdx.x;               // 2048 = B_*NCHUNK*8
    const int cg = blk & 7, chunk = (blk >> 3) & 63, b = blk >> 9;
    const int c = cg * 256 + threadIdx.x;
    const float w0 = ldw(cw, c * 3 + 0, fm);
    const float w1 = ldw(cw, c * 3 + 1, fm);
    const float w2 = ldw(cw, c * 3 + 2, fm);
    const float bc = ldw(cb, c, fm);
    const int t0 = chunk * CLEN;
    const float* g = gate + (size_t)b * T_ + t0;
    const __hip_bfloat16* px = xz + (size_t)b * T_ * E2 + c;

    float xm = (t0 > 0) ? bf2f(px[(size_t)(t0 - 1) * E2]) : 0.f;
    float xc = bf2f(px[(size_t)t0 * E2]);
    float h = 0.f;
#pragma unroll 4
    for (int i = 0; i < CLEN; i++) {
        const int t = t0 + i;
        const float xn = (t + 1 < T_) ? bf2f(px[(size_t)(t + 1) * E2]) : 0.f;
        const float val = w0 * xm + w1 * xc + w2 * xn + bc;
        const float gi = g[i];
        h = gi * h + (1.f - gi) * val;
        xm = xc; xc = xn;
    }
    r[((size_t)b * NCHUNK + chunk) * DI + c] = h;
}

// ---------------------------------------------------------------------------
// Pass B: preload all 64 rk into registers (64 independent loads in flight
// instead of 64 serial dependent round-trips) + P row in LDS, then run the
// h-chain. In-place r[b,k,c] := h_in of chunk k. Same arithmetic order.
// ---------------------------------------------------------------------------
__global__ __launch_bounds__(256)
void carry_fix(float* __restrict__ r, const float* __restrict__ P)
{
    __shared__ float Ps[NCHUNK];
    const int gid = blockIdx.x * 256 + threadIdx.x;   // 8192 = B_*DI
    const int b = gid >> 11, c = gid & 2047;
    if (threadIdx.x < NCHUNK) Ps[threadIdx.x] = P[b * NCHUNK + threadIdx.x];
    __syncthreads();

    float* base = r + (size_t)b * NCHUNK * DI + c;
    float rk[NCHUNK];
#pragma unroll
    for (int k = 0; k < NCHUNK; k++) rk[k] = base[(size_t)k * DI];
    float h = 0.f;
#pragma unroll
    for (int k = 0; k < NCHUNK; k++) {
        base[(size_t)k * DI] = h;
        h = Ps[k] * h + rk[k];
    }
}

// ---------------------------------------------------------------------------
// Pass C: re-scan with carry-in; y = h*silu(z) + D*val written over the
// Z-HALF slot it just read (x-half stays intact -> conv reads race-free).
// (R6 scalar config — proven best.)
// ---------------------------------------------------------------------------
__global__ __launch_bounds__(256)
void scan_apply(__hip_bfloat16* __restrict__ xz,
                const float* __restrict__ gate,
                const float* __restrict__ r,
                const void* __restrict__ cw, const void* __restrict__ cb,
                const void* __restrict__ Dp, const unsigned* __restrict__ flag)
{
    const int fm = (int)*flag;
    const int blk = blockIdx.x;               // 2048
    const int cg = blk & 7, chunk = (blk >> 3) & 63, b = blk >> 9;
    const int c = cg * 256 + threadIdx.x;
    const float w0 = ldw(cw, c * 3 + 0, fm);
    const float w1 = ldw(cw, c * 3 + 1, fm);
    const float w2 = ldw(cw, c * 3 + 2, fm);
    const float bc = ldw(cb, c, fm);
    const float Dc = ldw(Dp, c, fm);
    const int t0 = chunk * CLEN;
    const float* g = gate + (size_t)b * T_ + t0;
    const __hip_bfloat16* px = xz + (size_t)b * T_ * E2 + c;            // x-half
    __hip_bfloat16* pz = xz + (size_t)b * T_ * E2 + DI + c;             // z-half

    float h = r[((size_t)b * NCHUNK + chunk) * DI + c];
    float xm = (t0 > 0) ? bf2f(px[(size_t)(t0 - 1) * E2]) : 0.f;
    float xc = bf2f(px[(size_t)t0 * E2]);
#pragma unroll 4
    for (int i = 0; i < CLEN; i++) {
        const int t = t0 + i;
        const float xn = (t + 1 < T_) ? bf2f(px[(size_t)(t + 1) * E2]) : 0.f;
        const float val = w0 * xm + w1 * xc + w2 * xn + bc;
        const float gi = g[i];
        h = gi * h + (1.f - gi) * val;
        const float zv = bf2f(pz[(size_t)t * E2]);
        const float sil = zv / (1.f + __expf(-zv));
        pz[(size_t)t * E2] = __float2bfloat16(h * sil + Dc * val);
        xm = xc; xc = xn;
    }
}

// ---------------------------------------------------------------------------
extern "C" void kernel_launch(void* const* d_in, const int* in_sizes, int n_in,
                              void* d_out, int out_size, void* d_ws, size_t ws_size,
                              hipStream_t stream)
{
    // ws layout (proven size): xz[0,134217728) gate[..+65536) v[..+8704) flag
    const size_t REQUIRED = 134292480;
    if (ws_size < REQUIRED) return;   // finite-absmax diagnostic signature

    const void* x    = d_in[0];
    const void* wip  = d_in[1];  // [4096,1024]
    const void* cw   = d_in[2];  // [2048,1,3]
    const void* cb   = d_in[3];
    const void* xpw  = d_in[4];  // [96,2048]
    const void* dtw  = d_in[5];  // [2048,64]
    const void* dtb  = d_in[6];
    const void* Dp   = d_in[7];
    const void* wop  = d_in[8];  // [1024,2048]

    char* ws = (char*)d_ws;
    __hip_bfloat16* xz = (__hip_bfloat16*)ws;
    float* gate    = (float*)(ws + 134217728);
    float* v       = (float*)(ws + 134283264);
    float* wm      = v + 2052;                 // 65 floats, fits in v's 8704 B region
    unsigned* flag = (unsigned*)(ws + 134291968);

    // d_out scratch (67.1 MB, all dead before gemm2 writes final out):
    //   x_bf16   [0, 33554432)          16.8M elems
    //   wip_bf16 [33554432, 41943040)    4.2M elems
    //   r        [41943040, 44040192)    2 MB
    //   P        [44040192, 44041216)    1 KB
    //   u0/u1/u2 [44041216, 44065792)    3 x 8 KB
    //   gcpart   [44065792, 44065824)    32 B
    //   S0/S1/S2 [44065824, 44262432)    3 x 64 KB
    __hip_bfloat16* x_bf   = (__hip_bfloat16*)d_out;
    __hip_bfloat16* wip_bf = (__hip_bfloat16*)((char*)d_out + 33554432);
    float* r      = (float*)((char*)d_out + 41943040);
    float* P      = (float*)((char*)d_out + 44040192);
    float* u0     = (float*)((char*)d_out + 44041216);
    float* u1     = (float*)((char*)d_out + 44049408);
    float* u2     = (float*)((char*)d_out + 44057600);
    float* gcpart = (float*)((char*)d_out + 44065792);
    float* S0     = (float*)((char*)d_out + 44065824);
    float* S1     = (float*)((char*)d_out + 44131360);
    float* S2     = (float*)((char*)d_out + 44196896);
    // wop_bf16 lives in the x-half of xz rows 0..2047 (dead after scan_apply)
    // — NOT in d_out: gemm2's f32 C-write covers all of d_out and would evict
    // the B panel from L2 / race with B reads (R10 regression).
    __hip_bfloat16* wop_bf = xz;

    detect_k<<<1, 256, 0, stream>>>((const unsigned short*)x, flag);

    cvt_k<<<8192, 256, 0, stream>>>(x, x_bf, flag);       // 16777216 elems
    cvt_k<<<2048, 256, 0, stream>>>(wip, wip_bf, flag);   //  4194304 elems

    // precompute v: 65-block column-mean reduce, then 8-block mat-vec (+ u, cb-sum)
    precompute_wm_k<<<65, 256, 0, stream>>>(dtw, dtb, wm, flag);
    precompute_v2_k<<<8, 256, 0, stream>>>(xpw, wm, cw, cb, v, u0, u1, u2,
                                           gcpart, flag);

    // xz[16384,4096] = x_bf[16384,1024] * wip_bf^T   (C bf16)
    gemm256<<<dim3(64, 16), 512, 0, stream>>>(x_bf, wip_bf, xz,
                                              1024, 1024, 1024, E2, 0, flag);

    // gate: 4-row blocks with u-reuse -> boundary combine (+ fused P product)
    gate_dots_k<<<dim3(1024, B_), 256, 0, stream>>>(xz, u0, u1, u2, S0, S1, S2);
    gate_fin_k<<<64, 256, 0, stream>>>(S0, S1, S2, gcpart, v, gate, P);

    scan_chunks<<<2048, 256, 0, stream>>>(xz, gate, cw, cb, r, flag);
    carry_fix<<<32, 256, 0, stream>>>(r, P);
    scan_apply<<<2048, 256, 0, stream>>>(xz, gate, r, cw, cb, Dp, flag);

    // wop -> bf16 into xz x-half rows 0..2047 (row pitch E2); x-half now dead
    cvt_strided_k<<<1024, 256, 0, stream>>>(wop, wop_bf, flag);  // 2097152 elems

    // out[16384,1024] = y[16384,2048](z-half, stride E2) * wop_bf^T(stride E2)
    gemm256<<<dim3(64, 4), 512, 0, stream>>>(xz + DI, wop_bf, d_out,
                                             2048, E2, E2, DM, 1, flag);
}